// Round 8
// baseline (248.505 us; speedup 1.0000x reference)
//
#include <hip/hip_runtime.h>
#include <hip/hip_bf16.h>
#include <stdint.h>

// Problem constants
#define B_ 4
#define T_ 4096
#define I_ 1024
#define H_ 16
#define D_ 64
#define M_TOT (B_*T_)      // 16384
#define N_TOT (H_*D_*2)    // 2048, permuted: col = h*128 + k2*64 + d
#define K_TOT I_           // 1024

#define BM 256
#define BN 256
#define BK 32
#define NT (K_TOT/BK)               // 32
#define BUFE (BM*BK + BN*BK)        // 16384 elems = 32 KB per buffer

typedef __bf16 bf16;
typedef __attribute__((ext_vector_type(8))) __bf16 bf16x8;
typedef __attribute__((ext_vector_type(4))) float f32x4;

#define AS_G __attribute__((address_space(1)))
#define AS_L __attribute__((address_space(3)))

__device__ __forceinline__ void gld_lds16(const void* g, void* l) {
    __builtin_amdgcn_global_load_lds((const AS_G void*)g, (AS_L void*)l, 16, 0, 0);
}

// ---------------- pass 0: fused convert: X fp32->bf16 ; W (I,N) -> Wt (N',I) bf16 permuted ----------------
__global__ void k_prep(const float* __restrict__ x, const float* __restrict__ w,
                       bf16* __restrict__ xb, bf16* __restrict__ wt) {
    if (blockIdx.x < 2048) {
        int idx = blockIdx.x * 256 + threadIdx.x;
        const int n4 = (M_TOT * K_TOT) / 4;
        for (int i = idx; i < n4; i += 2048 * 256) {
            float4 f = reinterpret_cast<const float4*>(x)[i];
            union { bf16 h[4]; uint64_t u; } pk;
            pk.h[0] = (bf16)f.x; pk.h[1] = (bf16)f.y; pk.h[2] = (bf16)f.z; pk.h[3] = (bf16)f.w;
            reinterpret_cast<uint64_t*>(xb)[i] = pk.u;
        }
    } else {
        __shared__ float tile[32][33];
        int bid = blockIdx.x - 2048;
        int tn = bid % (N_TOT/32);
        int ti = bid / (N_TOT/32);
        int tid = threadIdx.x;
        int c = tid & 31, rgrp = tid >> 5;
        #pragma unroll
        for (int p = 0; p < 4; ++p) {
            int il = p * 8 + rgrp;
            int cn = tn*32 + c;                      // permuted output col
            int h = cn >> 7, k2 = (cn >> 6) & 1, d = cn & 63;
            int nsrc = (h << 7) + (d << 1) + k2;     // original col
            tile[il][c] = w[(ti*32 + il) * N_TOT + nsrc];
        }
        __syncthreads();
        #pragma unroll
        for (int p = 0; p < 4; ++p) {
            int nl = p * 8 + rgrp;
            wt[(size_t)(tn*32 + nl) * K_TOT + ti*32 + c] = (bf16)tile[c][nl];
        }
    }
}

// ---------------- pass 1: GEMM + silu + fused score + fused chunk-aggregates ----------------
// 256x256 tile, BK=32, 4 LDS buffers, counted vmcnt(8), 8 waves (2M x 4N), per-wave 128x64.
// LDS row = 64B (4 slots of 16B); slot swizzle: sl' = sl ^ ((row>>1)&3).
__device__ __forceinline__ bf16x8 frag(const bf16* base, int row, int g) {
    const char* p = (const char*)base + row * 64 + (((g ^ ((row >> 1) & 3)) & 3) << 4);
    return *reinterpret_cast<const bf16x8*>(p);
}

__global__ __launch_bounds__(512, 2)
void k_gemm(const bf16* __restrict__ xb, const bf16* __restrict__ wt,
            const float* __restrict__ q, bf16* __restrict__ v,
            float* __restrict__ s, float* __restrict__ agg) {
    extern __shared__ __attribute__((aligned(16))) char smem[];
    bf16* lds = (bf16*)smem;                       // 4 * BUFE elems
    float* s_lds = (float*)(smem + 4*BUFE*2);      // [2][256]

    const int tid = threadIdx.x;
    const int wid = tid >> 6, lane = tid & 63;
    const int wm = wid >> 2, wn = wid & 3;
    const int g = lane >> 4, r16 = lane & 15;

    // XCD swizzle: 512 blocks, 64 contiguous per XCD
    int bid = blockIdx.x;
    int swz = (bid & 7) * 64 + (bid >> 3);
    int bm = swz >> 3, bn = swz & 7;
    const int row0 = bm * BM, n0 = bn * BN;

    auto stageA = [&](int t) {
        bf16* dst = lds + (t & 3) * BUFE;
        int k0 = t * BK;
        #pragma unroll
        for (int j = 0; j < 2; ++j) {
            int c = j * 512 + tid;
            int row = c >> 2, sl = c & 3;
            int koff = ((sl ^ ((row >> 1) & 3)) & 3) << 3;
            gld_lds16(xb + (size_t)(row0 + row) * K_TOT + k0 + koff, (char*)dst + c * 16);
        }
    };
    auto stageB = [&](int t) {
        bf16* dst = lds + (t & 3) * BUFE + BM * BK;
        int k0 = t * BK;
        #pragma unroll
        for (int j = 0; j < 2; ++j) {
            int c = j * 512 + tid;
            int row = c >> 2, sl = c & 3;
            int koff = ((sl ^ ((row >> 1) & 3)) & 3) << 3;
            gld_lds16(wt + (size_t)(n0 + row) * K_TOT + k0 + koff, (char*)dst + c * 16);
        }
    };

    f32x4 acc[8][4];
    #pragma unroll
    for (int i = 0; i < 8; ++i)
        #pragma unroll
        for (int j = 0; j < 4; ++j) acc[i][j] = (f32x4){0.f,0.f,0.f,0.f};

    // prologue: tiles 0,1,2 staged (12 loads/thread); drain tile 0 only
    stageA(0); stageB(0);
    stageA(1); stageB(1);
    stageA(2); stageB(2);
    asm volatile("s_waitcnt vmcnt(8)" ::: "memory");
    __builtin_amdgcn_s_barrier();

    #pragma unroll 1
    for (int t = 0; t < NT; ++t) {
        const bf16* Ab = lds + (t & 3) * BUFE;
        const bf16* Bb = Ab + BM * BK;
        const bool st = (t + 3 < NT);
        bf16x8 a[4], b[4];

        // ---- P0: mi 0-3 ----
        #pragma unroll
        for (int mi = 0; mi < 4; ++mi) a[mi] = frag(Ab, wm*128 + mi*16 + r16, g);
        #pragma unroll
        for (int ni = 0; ni < 4; ++ni) b[ni] = frag(Bb, wn*64 + ni*16 + r16, g);
        if (st) stageA(t + 3);
        __builtin_amdgcn_s_barrier();
        // pin: ds_reads above complete here; nothing may sink below this point (rule 18)
        asm volatile("s_waitcnt lgkmcnt(0)" ::: "memory");
        __builtin_amdgcn_sched_barrier(0);
        __builtin_amdgcn_s_setprio(1);
        #pragma unroll
        for (int mi = 0; mi < 4; ++mi)
            #pragma unroll
            for (int ni = 0; ni < 4; ++ni)
                acc[mi][ni] = __builtin_amdgcn_mfma_f32_16x16x32_bf16(a[mi], b[ni], acc[mi][ni], 0,0,0);
        __builtin_amdgcn_s_setprio(0);
        __builtin_amdgcn_s_barrier();

        // ---- P1: mi 4-7 (b reused) ----
        #pragma unroll
        for (int mi = 0; mi < 4; ++mi) a[mi] = frag(Ab, wm*128 + (mi+4)*16 + r16, g);
        if (st) stageB(t + 3);
        __builtin_amdgcn_s_barrier();
        asm volatile("s_waitcnt lgkmcnt(0)" ::: "memory");
        __builtin_amdgcn_sched_barrier(0);
        __builtin_amdgcn_s_setprio(1);
        #pragma unroll
        for (int mi = 0; mi < 4; ++mi)
            #pragma unroll
            for (int ni = 0; ni < 4; ++ni)
                acc[mi+4][ni] = __builtin_amdgcn_mfma_f32_16x16x32_bf16(a[mi], b[ni], acc[mi+4][ni], 0,0,0);
        __builtin_amdgcn_s_setprio(0);
        if (t < NT - 1) {
            if (t < NT - 3)       asm volatile("s_waitcnt vmcnt(8)" ::: "memory");
            else if (t == NT - 3) asm volatile("s_waitcnt vmcnt(4)" ::: "memory");
            else                  asm volatile("s_waitcnt vmcnt(0)" ::: "memory");
            __builtin_amdgcn_s_barrier();
        }
    }

    // ---- epilogue: silu all acc in place ----
    #pragma unroll
    for (int mi = 0; mi < 8; ++mi)
        #pragma unroll
        for (int ni = 0; ni < 4; ++ni)
            #pragma unroll
            for (int r = 0; r < 4; ++r) {
                float x = acc[mi][ni][r];
                acc[mi][ni][r] = x / (1.0f + __expf(-x));
            }

    const int hloc = wn >> 1;
    const int h = bn * 2 + hloc;

    if ((wn & 1) == 0) {
        // k-wave: score s[row,h] = sum_d silu(k)*q[h,d]
        float qv[4];
        #pragma unroll
        for (int ni = 0; ni < 4; ++ni) qv[ni] = q[h * D_ + ni*16 + r16];
        #pragma unroll
        for (int mi = 0; mi < 8; ++mi) {
            #pragma unroll
            for (int r = 0; r < 4; ++r) {
                float part = acc[mi][0][r]*qv[0] + acc[mi][1][r]*qv[1]
                           + acc[mi][2][r]*qv[2] + acc[mi][3][r]*qv[3];
                part += __shfl_xor(part, 1);
                part += __shfl_xor(part, 2);
                part += __shfl_xor(part, 4);
                part += __shfl_xor(part, 8);
                if (r16 == 0) {
                    int rl = wm*128 + mi*16 + g*4 + r;
                    s[(row0 + rl) * H_ + h] = part;
                    s_lds[hloc*256 + rl] = part;
                }
            }
        }
    } else {
        // v-wave: store silu'd v as bf16
        #pragma unroll
        for (int mi = 0; mi < 8; ++mi)
            #pragma unroll
            for (int ni = 0; ni < 4; ++ni)
                #pragma unroll
                for (int r = 0; r < 4; ++r) {
                    int row = row0 + wm*128 + mi*16 + g*4 + r;
                    v[(size_t)row * (H_*D_) + h*D_ + ni*16 + r16] = (bf16)acc[mi][ni][r];
                }
    }
    __syncthreads();

    if (wn & 1) {
        // chunk aggregates: wave covers 128 rows = 2 chunks of 64
        #pragma unroll
        for (int c = 0; c < 2; ++c) {
            float sv[16];
            #pragma unroll
            for (int mm = 0; mm < 4; ++mm)
                #pragma unroll
                for (int r = 0; r < 4; ++r)
                    sv[mm*4+r] = s_lds[hloc*256 + wm*128 + (c*4+mm)*16 + g*4 + r];
            float m_l = sv[0];
            #pragma unroll
            for (int i = 1; i < 16; ++i) m_l = fmaxf(m_l, sv[i]);
            float u_l = 0.f, w_l[4] = {0.f, 0.f, 0.f, 0.f};
            #pragma unroll
            for (int mm = 0; mm < 4; ++mm)
                #pragma unroll
                for (int r = 0; r < 4; ++r) {
                    float e = __expf(sv[mm*4+r] - m_l);
                    u_l += e;
                    #pragma unroll
                    for (int ni = 0; ni < 4; ++ni)
                        w_l[ni] += e * acc[c*4+mm][ni][r];
                }
            // combine across the 4 g-groups (lanes xor 16, 32)
            #pragma unroll
            for (int off = 16; off <= 32; off <<= 1) {
                float m2 = __shfl_xor(m_l, off);
                float u2 = __shfl_xor(u_l, off);
                float w2[4];
                #pragma unroll
                for (int ni = 0; ni < 4; ++ni) w2[ni] = __shfl_xor(w_l[ni], off);
                float mn = fmaxf(m_l, m2);
                float ea = __expf(m_l - mn), eb = __expf(m2 - mn);
                u_l = u_l * ea + u2 * eb;
                #pragma unroll
                for (int ni = 0; ni < 4; ++ni) w_l[ni] = w_l[ni]*ea + w2[ni]*eb;
                m_l = mn;
            }
            if (g == 0) {
                int rbase = row0 + wm*128 + c*64;
                int bb = rbase >> 12, tloc = rbase & (T_-1);
                float* a = agg + (size_t)(((bb*H_ + h) << 6) + (tloc >> 6)) * 66;
                if (r16 == 0) { a[0] = m_l; a[1] = u_l; }
                #pragma unroll
                for (int ni = 0; ni < 4; ++ni) a[2 + ni*16 + r16] = w_l[ni];
            }
        }
    }
}

// ---------------- scan phase C (with inline exclusive chunk-prefix): out = w/u ----------------
__global__ void k_scanC(const float* __restrict__ s, const bf16* __restrict__ v,
                        const float* __restrict__ agg, float* __restrict__ out) {
    int C = blockIdx.x * 4 + (threadIdx.x >> 6);
    int lane = threadIdx.x & 63;
    int p = C >> 6, c = C & 63;
    int b = p >> 4, h = p & 15;
    int rbase = b * T_ + c * 64;

    // inline exclusive prefix over chunks [0, c) of this (b,h)
    float m = -INFINITY, u = 0.f, w = 0.f;
    const float* ag = agg + (size_t)p * 64 * 66;
    for (int j = 0; j < c; ++j) {
        const float* a = ag + j * 66;
        float ma = a[0], ua = a[1], wa = a[2 + lane];
        float mn = fmaxf(m, ma);
        float ec = __expf(m - mn), ea = __expf(ma - mn);
        u = u * ec + ua * ea;
        w = w * ec + wa * ea;
        m = mn;
    }

    // local rescan with carry-in
    const bf16* vbase = v + h * D_ + lane;
    #pragma unroll 4
    for (int i = 0; i < 64; ++i) {
        int r = rbase + i;
        float sv = s[r * H_ + h];
        float vv = (float)vbase[(size_t)r * (H_*D_)];
        float mn = fmaxf(m, sv);
        float ea = __expf(m - mn);
        float eb = __expf(sv - mn);
        u = u * ea + eb;
        w = w * ea + vv * eb;
        m = mn;
        out[(size_t)r * (H_*D_) + h * D_ + lane] = __fdividef(w, u);
    }
}

extern "C" void kernel_launch(void* const* d_in, const int* in_sizes, int n_in,
                              void* d_out, int out_size, void* d_ws, size_t ws_size,
                              hipStream_t stream) {
    (void)in_sizes; (void)n_in; (void)out_size; (void)ws_size;
    const float* x  = (const float*)d_in[0];
    const float* wk = (const float*)d_in[1];
    const float* qk = (const float*)d_in[2];
    float* out = (float*)d_out;
    char* ws = (char*)d_ws;

    bf16*  xb  = (bf16*) (ws);                      // 33,554,432
    bf16*  wt  = (bf16*) (ws + 33554432ull);        //  4,194,304
    bf16*  v   = (bf16*) (ws + 37748736ull);        // 33,554,432
    float* s   = (float*)(ws + 71303168ull);        //  1,048,576
    float* agg = (float*)(ws + 72351744ull);        //  1,081,344

    hipLaunchKernelGGL(k_prep,  dim3(4096), dim3(256), 0, stream, x, wk, xb, wt);
    hipLaunchKernelGGL(k_gemm,  dim3((M_TOT/BM)*(N_TOT/BN)), dim3(512), 4*BUFE*2 + 2048, stream,
                       xb, wt, qk, v, s, agg);
    hipLaunchKernelGGL(k_scanC, dim3(B_*H_*64/4), dim3(256), 0, stream, s, v, agg, out);
}